// Round 1
// baseline (195.677 us; speedup 1.0000x reference)
//
#include <hip/hip_runtime.h>

#define BATCH   2048
#define NPAR    256
#define NF      32
#define NG      16
#define NBR     4
#define OFS     262144
#define DOUT    128
#define NROWSX  (OFS + NPAR*BATCH)     // 786432 rows of x
#define MROWS   (NPAR*BATCH)           // 524288 parent rows
#define NTILES  (MROWS/16)             // 32768 16-row tiles
#define CHBASE  (NROWSX*NF)            // float offset of children region in out

typedef short bf16x8 __attribute__((ext_vector_type(8)));   // 8 bf16 bit-patterns
typedef float f32x4  __attribute__((ext_vector_type(4)));

__device__ __forceinline__ unsigned short f2bf(float f){
  unsigned int u = __float_as_uint(f);
  u += 0x7FFFu + ((u >> 16) & 1u);          // RNE
  return (unsigned short)(u >> 16);
}

// G1[e][j] = b1[j] + sum_k global[e][k] * W1[32+k][j]
__global__ void k_g1(const float* __restrict__ gf, const float* __restrict__ W1,
                     const float* __restrict__ b1, float* __restrict__ G1){
  int idx = blockIdx.x*blockDim.x + threadIdx.x;
  if (idx >= BATCH*DOUT) return;
  int e = idx >> 7, j = idx & 127;
  float s = b1[j];
  const float* grow = gf + e*NG;
  const float* w = W1 + NF*DOUT + j;
  #pragma unroll
  for (int k = 0; k < NG; k++) s = fmaf(grow[k], w[k*DOUT], s);
  G1[idx] = s;
}

__global__ void k_copy(const float4* __restrict__ src, float4* __restrict__ dst){
  const int n = NROWSX*NF/4;
  for (int i = blockIdx.x*blockDim.x + threadIdx.x; i < n; i += gridDim.x*blockDim.x)
    dst[i] = src[i];
}

__global__ __launch_bounds__(256) void k_mlp(
    const float* __restrict__ x, const int* __restrict__ pidx,
    const float* __restrict__ W1, const float* __restrict__ W2,
    const float* __restrict__ b2, const float* __restrict__ G1,
    float* __restrict__ out)
{
  __shared__ uint4 ldsB2[2048];   // 32 KB: W2 B-fragments, [frag(kk*8+n)][lane] * 16B
  __shared__ uint4 ldsH1[1024];   // 16 KB: per-wave 4KB h1 tile (bf16, swizzled)

  const int tid  = threadIdx.x;
  const int lane = tid & 63;
  const int wv   = tid >> 6;
  const int r15  = lane & 15;
  const int g    = lane >> 4;

  // ---- stage W2 fragments into LDS (once per block) ----
  for (int p = tid; p < 32*64; p += 256){
    int f = p >> 6, l = p & 63;
    int kk = f >> 3, n = f & 7;
    int krow = 32*kk + 8*(l >> 4);
    int col  = 16*n + (l & 15);
    union { uint4 q; unsigned short u[8]; } w;
    #pragma unroll
    for (int e = 0; e < 8; e++) w.u[e] = f2bf(W2[(krow + e)*DOUT + col]);
    ldsB2[p] = w.q;
  }

  // ---- W1 (feature half) B-fragments in registers ----
  bf16x8 b1f[8];
  {
    int kb = 8*g;
    #pragma unroll
    for (int n = 0; n < 8; n++){
      union { bf16x8 v; unsigned short u[8]; } w;
      #pragma unroll
      for (int e = 0; e < 8; e++) w.u[e] = f2bf(W1[(kb + e)*DOUT + 16*n + r15]);
      b1f[n] = w.v;
    }
  }
  float b2v[8];
  #pragma unroll
  for (int n = 0; n < 8; n++) b2v[n] = b2[16*n + r15];

  __syncthreads();

  char* h1base = (char*)ldsH1 + wv*4096;
  const bf16x8* B2f = (const bf16x8*)ldsB2;

  for (int j = 0; j < 4; j++){
    const int tl   = blockIdx.x*16 + j*4 + wv;   // tile index
    const int row0 = tl*16;

    // A1 fragment: row = r15, k = 8*g + e
    const int idxA = pidx[row0 + r15];
    const float* ap = x + idxA*NF + 8*g;
    float4 a0 = *(const float4*)ap;
    float4 a1 = *(const float4*)(ap + 4);
    union { bf16x8 v; unsigned short u[8]; } af;
    af.u[0]=f2bf(a0.x); af.u[1]=f2bf(a0.y); af.u[2]=f2bf(a0.z); af.u[3]=f2bf(a0.w);
    af.u[4]=f2bf(a1.x); af.u[5]=f2bf(a1.y); af.u[6]=f2bf(a1.z); af.u[7]=f2bf(a1.w);

    // indices for the 4 accumulator rows this lane owns (rows 4g+r)
    int idxR[4];
    #pragma unroll
    for (int r = 0; r < 4; r++) idxR[r] = pidx[row0 + 4*g + r];

    // GEMM1: acc preloaded with G1 (bias + global part folded in)
    f32x4 acc[8];
    #pragma unroll
    for (int n = 0; n < 8; n++){
      #pragma unroll
      for (int r = 0; r < 4; r++)
        acc[n][r] = G1[(idxR[r] & (BATCH-1))*DOUT + 16*n + r15];
    }
    #pragma unroll
    for (int n = 0; n < 8; n++)
      acc[n] = __builtin_amdgcn_mfma_f32_16x16x32_bf16(af.v, b1f[n], acc[n], 0, 0, 0);

    // leaky-relu, convert to bf16, scatter into swizzled LDS tile [16][128]
    #pragma unroll
    for (int n = 0; n < 8; n++){
      #pragma unroll
      for (int r = 0; r < 4; r++){
        float v = acc[n][r];
        v = v > 0.0f ? v : 0.01f*v;
        int row = 4*g + r;
        int off = row*256 + (16*n + r15)*2;
        off ^= (row & 7) << 4;
        *(unsigned short*)(h1base + off) = f2bf(v);
      }
    }
    // wave-private LDS: compiler orders via lgkmcnt; no barrier needed.

    // GEMM2: A2 row = r15, k = 32*kk + 8*g + e  (swizzled b128 reads)
    f32x4 acc2[8];
    #pragma unroll
    for (int n = 0; n < 8; n++){ f32x4 z = {0.f,0.f,0.f,0.f}; acc2[n] = z; }
    #pragma unroll
    for (int kk = 0; kk < 4; kk++){
      int roff = r15*256 + g*16 + kk*64;
      roff ^= (r15 & 7) << 4;
      bf16x8 a2 = *(const bf16x8*)(h1base + roff);
      #pragma unroll
      for (int n = 0; n < 8; n++)
        acc2[n] = __builtin_amdgcn_mfma_f32_16x16x32_bf16(a2, B2f[(kk*8 + n)*64 + lane], acc2[n], 0, 0, 0);
    }

    // epilogue: + b2 + repeat_interleave residual, scatter to children layout
    const int p  = row0 >> 11;           // parent index (tiles never cross parents)
    const int b0 = row0 & (BATCH-1);
    #pragma unroll
    for (int n = 0; n < 8; n++){
      int c  = 16*n + r15;               // column in [0,128)
      int br = c >> 5, fc = c & 31;
      int rc = c >> 2;                   // residual feature = c//4
      int obase = CHBASE + ((p*NBR + br)*BATCH + b0 + 4*g)*NF + fc;
      #pragma unroll
      for (int r = 0; r < 4; r++){
        float v = acc2[n][r] + b2v[n] + x[idxR[r]*NF + rc];
        out[obase + r*NF] = v;
      }
    }
  }
}

extern "C" void kernel_launch(void* const* d_in, const int* in_sizes, int n_in,
                              void* d_out, int out_size, void* d_ws, size_t ws_size,
                              hipStream_t stream){
  const float* x   = (const float*)d_in[0];
  const float* gf  = (const float*)d_in[1];
  const int*   pidx= (const int*)d_in[2];
  const float* W1  = (const float*)d_in[3];
  const float* b1  = (const float*)d_in[4];
  const float* W2  = (const float*)d_in[5];
  const float* b2  = (const float*)d_in[6];
  float* out = (float*)d_out;
  float* G1  = (float*)d_ws;             // 2048*128*4 = 1 MB scratch

  k_g1  <<<(BATCH*DOUT)/256, 256, 0, stream>>>(gf, W1, b1, G1);
  k_copy<<<4096, 256, 0, stream>>>((const float4*)x, (float4*)out);
  k_mlp <<<NTILES/16, 256, 0, stream>>>(x, pidx, W1, W2, b2, G1, out);
}